// Round 1
// baseline (924.266 us; speedup 1.0000x reference)
//
#include <hip/hip_runtime.h>

#define N_NODES 5000
#define IN_DIM  1280
#define HID     128
#define ALPHA   0.2f

__device__ __forceinline__ float leaky(float v) { return v >= 0.f ? v : ALPHA * v; }

// monotone map float -> unsigned so unsigned atomicMax == float max
__device__ __forceinline__ unsigned fmap(float f) {
  unsigned u = __float_as_uint(f);
  return (u & 0x80000000u) ? ~u : (u | 0x80000000u);
}
__device__ __forceinline__ float funmap(unsigned u) {
  return (u & 0x80000000u) ? __uint_as_float(u & 0x7fffffffu) : __uint_as_float(~u);
}

// h = relu(x @ W_in + b_in)   [5000,1280]x[1280,128]
__global__ __launch_bounds__(256) void k_gemm_in(const float* __restrict__ x,
    const float* __restrict__ W, const float* __restrict__ b, float* __restrict__ h) {
  const int col = threadIdx.x & 127;
  const int rg  = threadIdx.x >> 7;        // 0..1
  const int row0 = blockIdx.x * 16;
  __shared__ float xs[16][128];
  float acc[8] = {0.f,0.f,0.f,0.f,0.f,0.f,0.f,0.f};
  for (int k0 = 0; k0 < IN_DIM; k0 += 128) {
#pragma unroll
    for (int t = 0; t < 8; ++t) {
      int idx = threadIdx.x + t * 256;
      int r = idx >> 7, c = idx & 127;
      int row = row0 + r;
      xs[r][c] = (row < N_NODES) ? x[row * IN_DIM + k0 + c] : 0.f;
    }
    __syncthreads();
#pragma unroll 8
    for (int kq = 0; kq < 32; ++kq) {
      const float w0 = W[(k0 + kq * 4 + 0) * HID + col];
      const float w1 = W[(k0 + kq * 4 + 1) * HID + col];
      const float w2 = W[(k0 + kq * 4 + 2) * HID + col];
      const float w3 = W[(k0 + kq * 4 + 3) * HID + col];
#pragma unroll
      for (int r = 0; r < 8; ++r) {
        const float4 xv = *reinterpret_cast<const float4*>(&xs[rg * 8 + r][kq * 4]);
        acc[r] = fmaf(xv.x, w0, acc[r]);
        acc[r] = fmaf(xv.y, w1, acc[r]);
        acc[r] = fmaf(xv.z, w2, acc[r]);
        acc[r] = fmaf(xv.w, w3, acc[r]);
      }
    }
    __syncthreads();
  }
  const float bias = b[col];
#pragma unroll
  for (int r = 0; r < 8; ++r) {
    int row = row0 + rg * 8 + r;
    if (row < N_NODES) h[row * HID + col] = fmaxf(acc[r] + bias, 0.f);
  }
}

// xl = h@W_l + b_l ; xr = h@W_r + b_r   (K=128, one LDS stage)
__global__ __launch_bounds__(256) void k_gemm_lr(const float* __restrict__ h,
    const float* __restrict__ Wl, const float* __restrict__ bl,
    const float* __restrict__ Wr, const float* __restrict__ br,
    float* __restrict__ xl, float* __restrict__ xr) {
  const int col = threadIdx.x & 127;
  const int rg  = threadIdx.x >> 7;
  const int row0 = blockIdx.x * 16;
  __shared__ float hs[16][128];
  float accl[8] = {0.f,0.f,0.f,0.f,0.f,0.f,0.f,0.f};
  float accr[8] = {0.f,0.f,0.f,0.f,0.f,0.f,0.f,0.f};
#pragma unroll
  for (int t = 0; t < 8; ++t) {
    int idx = threadIdx.x + t * 256;
    int r = idx >> 7, c = idx & 127;
    int row = row0 + r;
    hs[r][c] = (row < N_NODES) ? h[row * HID + c] : 0.f;
  }
  __syncthreads();
#pragma unroll 4
  for (int kq = 0; kq < 32; ++kq) {
    float wl0 = Wl[(kq * 4 + 0) * HID + col], wr0 = Wr[(kq * 4 + 0) * HID + col];
    float wl1 = Wl[(kq * 4 + 1) * HID + col], wr1 = Wr[(kq * 4 + 1) * HID + col];
    float wl2 = Wl[(kq * 4 + 2) * HID + col], wr2 = Wr[(kq * 4 + 2) * HID + col];
    float wl3 = Wl[(kq * 4 + 3) * HID + col], wr3 = Wr[(kq * 4 + 3) * HID + col];
#pragma unroll
    for (int r = 0; r < 8; ++r) {
      const float4 xv = *reinterpret_cast<const float4*>(&hs[rg * 8 + r][kq * 4]);
      accl[r] = fmaf(xv.x, wl0, accl[r]); accr[r] = fmaf(xv.x, wr0, accr[r]);
      accl[r] = fmaf(xv.y, wl1, accl[r]); accr[r] = fmaf(xv.y, wr1, accr[r]);
      accl[r] = fmaf(xv.z, wl2, accl[r]); accr[r] = fmaf(xv.z, wr2, accr[r]);
      accl[r] = fmaf(xv.w, wl3, accl[r]); accr[r] = fmaf(xv.w, wr3, accr[r]);
    }
  }
  const float biasl = bl[col], biasr = br[col];
#pragma unroll
  for (int r = 0; r < 8; ++r) {
    int row = row0 + rg * 8 + r;
    if (row < N_NODES) {
      xl[row * HID + col] = accl[r] + biasl;
      xr[row * HID + col] = accr[r] + biasr;
    }
  }
}

// per-edge score + segment max (self-loops appended at e >= E)
__global__ __launch_bounds__(256) void k_score(const float* __restrict__ xl,
    const float* __restrict__ xr, const float* __restrict__ att,
    const int* __restrict__ ei, int E, int ET,
    float* __restrict__ score, unsigned* __restrict__ m) {
  int e = blockIdx.x * blockDim.x + threadIdx.x;
  if (e >= ET) return;
  const int src = (e < E) ? ei[e]     : (e - E);
  const int dst = (e < E) ? ei[E + e] : (e - E);
  const float4* pl = reinterpret_cast<const float4*>(xl + (size_t)src * HID);
  const float4* pr = reinterpret_cast<const float4*>(xr + (size_t)dst * HID);
  const float4* pa = reinterpret_cast<const float4*>(att);
  float sc = 0.f;
#pragma unroll 8
  for (int q = 0; q < 32; ++q) {
    const float4 a = pl[q], bq = pr[q], at = pa[q];
    sc += leaky(a.x + bq.x) * at.x;
    sc += leaky(a.y + bq.y) * at.y;
    sc += leaky(a.z + bq.z) * at.z;
    sc += leaky(a.w + bq.w) * at.w;
  }
  score[e] = sc;
  atomicMax(&m[dst], fmap(sc));
}

// ex = exp(score - m[dst]); s[dst] += ex; num[dst,:] += ex * xl[src,:]
__global__ __launch_bounds__(256) void k_scatter(const float* __restrict__ xl,
    const int* __restrict__ ei, int E, int ET,
    const float* __restrict__ score, const unsigned* __restrict__ m,
    float* __restrict__ s, float* __restrict__ num) {
  const int e = blockIdx.x * 2 + (threadIdx.x >> 7);
  const int j = threadIdx.x & 127;
  if (e >= ET) return;
  const int src = (e < E) ? ei[e]     : (e - E);
  const int dst = (e < E) ? ei[E + e] : (e - E);
  const float ex = expf(score[e] - funmap(m[dst]));
  if (j == 0) atomicAdd(&s[dst], ex);
  atomicAdd(&num[dst * HID + j], ex * xl[src * HID + j]);
}

// v = leaky(num/s + gat_bias)
__global__ __launch_bounds__(256) void k_v(const float* __restrict__ num,
    const float* __restrict__ s, const float* __restrict__ gb, float* __restrict__ v) {
  int i = blockIdx.x * blockDim.x + threadIdx.x;
  if (i >= N_NODES * HID) return;
  float val = num[i] / s[i >> 7] + gb[i & 127];
  v[i] = leaky(val);
}

// out128[j] = sum_i v[i] * W1[i*128+j]   (328 MB stream, HBM-bound)
__global__ __launch_bounds__(256) void k_matvec(const float* __restrict__ v,
    const float* __restrict__ W1, float* __restrict__ out128) {
  const int c  = threadIdx.x & 31;   // col quad: cols 4c..4c+3
  const int rr = threadIdx.x >> 5;   // 0..7 row group
  float4 acc = make_float4(0.f, 0.f, 0.f, 0.f);
  const int total = N_NODES * HID;
  for (int row = blockIdx.x * 8 + rr; row < total; row += gridDim.x * 8) {
    const float vv = v[row];
    const float4 w = *reinterpret_cast<const float4*>(&W1[(size_t)row * HID + c * 4]);
    acc.x = fmaf(vv, w.x, acc.x);
    acc.y = fmaf(vv, w.y, acc.y);
    acc.z = fmaf(vv, w.z, acc.z);
    acc.w = fmaf(vv, w.w, acc.w);
  }
  __shared__ float part[8][128];
  *reinterpret_cast<float4*>(&part[rr][c * 4]) = acc;
  __syncthreads();
  if (rr == 0) {
    float4 sum = make_float4(0.f, 0.f, 0.f, 0.f);
#pragma unroll
    for (int g = 0; g < 8; ++g) {
      const float4 p = *reinterpret_cast<const float4*>(&part[g][c * 4]);
      sum.x += p.x; sum.y += p.y; sum.z += p.z; sum.w += p.w;
    }
    atomicAdd(&out128[c * 4 + 0], sum.x);
    atomicAdd(&out128[c * 4 + 1], sum.y);
    atomicAdd(&out128[c * 4 + 2], sum.z);
    atomicAdd(&out128[c * 4 + 3], sum.w);
  }
}

// y = relu(out128 + b1); out = y @ W2 + b2
__global__ void k_final(const float* __restrict__ out128, const float* __restrict__ b1,
                        const float* __restrict__ W2, const float* __restrict__ b2,
                        float* __restrict__ out) {
  __shared__ float red[128];
  const int j = threadIdx.x;
  const float y = fmaxf(out128[j] + b1[j], 0.f);
  red[j] = y * W2[j];
  __syncthreads();
  if (j == 0) {
    float t = 0.f;
    for (int k = 0; k < 128; ++k) t += red[k];
    out[0] = t + b2[0];
  }
}

extern "C" void kernel_launch(void* const* d_in, const int* in_sizes, int n_in,
                              void* d_out, int out_size, void* d_ws, size_t ws_size,
                              hipStream_t stream) {
  const float* x    = (const float*)d_in[0];
  const int*   ei   = (const int*)  d_in[1];
  const float* W_in = (const float*)d_in[2];
  const float* b_in = (const float*)d_in[3];
  const float* W_l  = (const float*)d_in[4];
  const float* b_l  = (const float*)d_in[5];
  const float* W_r  = (const float*)d_in[6];
  const float* b_r  = (const float*)d_in[7];
  const float* att  = (const float*)d_in[8];
  const float* gb   = (const float*)d_in[9];
  const float* W1   = (const float*)d_in[10];
  const float* b1   = (const float*)d_in[11];
  const float* W2   = (const float*)d_in[12];
  const float* b2   = (const float*)d_in[13];
  float* out = (float*)d_out;

  const int E  = in_sizes[1] / 2;
  const int ET = E + N_NODES;

  float* ws = (float*)d_ws;
  float*    h      = ws;                               // 640000
  float*    xl     = ws + 640000;                      // 640000
  float*    xr     = ws + 1280000;                     // 640000
  float*    num    = ws + 1920000;                     // 640000
  float*    v      = ws + 2560000;                     // 640000
  float*    score  = ws + 3200000;                     // ET
  unsigned* m      = (unsigned*)(ws + 3200000 + ET);   // N_NODES
  float*    s      = ws + 3200000 + ET + N_NODES;      // N_NODES
  float*    out128 = s + N_NODES;                      // 128

  hipMemsetAsync(num,    0, (size_t)N_NODES * HID * sizeof(float), stream);
  hipMemsetAsync(m,      0, (size_t)N_NODES * sizeof(unsigned), stream);
  hipMemsetAsync(s,      0, (size_t)N_NODES * sizeof(float), stream);
  hipMemsetAsync(out128, 0, (size_t)HID * sizeof(float), stream);

  k_gemm_in <<<(N_NODES + 15) / 16, 256, 0, stream>>>(x, W_in, b_in, h);
  k_gemm_lr <<<(N_NODES + 15) / 16, 256, 0, stream>>>(h, W_l, b_l, W_r, b_r, xl, xr);
  k_score   <<<(ET + 255) / 256,    256, 0, stream>>>(xl, xr, att, ei, E, ET, score, m);
  k_scatter <<<(ET + 1) / 2,        256, 0, stream>>>(xl, ei, E, ET, score, m, s, num);
  k_v       <<<(N_NODES * HID + 255) / 256, 256, 0, stream>>>(num, s, gb, v);
  k_matvec  <<<2048, 256, 0, stream>>>(v, W1, out128);
  k_final   <<<1, 128, 0, stream>>>(out128, b1, W2, b2, out);
}

// Round 2
// 736.613 us; speedup vs baseline: 1.2548x; 1.2548x over previous
//
#include <hip/hip_runtime.h>
#include <math.h>

#define N_NODES 5000
#define IN_DIM  1280
#define HID     128
#define ALPHA   0.2f

__device__ __forceinline__ float leaky(float v) { return v >= 0.f ? v : ALPHA * v; }

// ---------------- GEMM 1: hp[ky] = x @ W_in (split-K halves, no bias) ----------------
__global__ __launch_bounds__(256) void k_gemm_in(const float* __restrict__ x,
    const float* __restrict__ W, float* __restrict__ hp) {
  const int col  = threadIdx.x & 127;
  const int rg   = threadIdx.x >> 7;       // 0..1
  const int row0 = blockIdx.x * 16;
  const int kbase = blockIdx.y * 640;      // split-K: 2 halves of 640
  __shared__ float xs[16][128];
  float acc[8] = {0.f,0.f,0.f,0.f,0.f,0.f,0.f,0.f};
  for (int k0 = 0; k0 < 640; k0 += 128) {
#pragma unroll
    for (int t = 0; t < 8; ++t) {
      int idx = threadIdx.x + t * 256;
      int r = idx >> 7, c = idx & 127;
      int row = row0 + r;
      xs[r][c] = (row < N_NODES) ? x[(size_t)row * IN_DIM + kbase + k0 + c] : 0.f;
    }
    __syncthreads();
#pragma unroll 8
    for (int kq = 0; kq < 32; ++kq) {
      const int kk = kbase + k0 + kq * 4;
      const float w0 = W[(kk + 0) * HID + col];
      const float w1 = W[(kk + 1) * HID + col];
      const float w2 = W[(kk + 2) * HID + col];
      const float w3 = W[(kk + 3) * HID + col];
#pragma unroll
      for (int r = 0; r < 8; ++r) {
        const float4 xv = *reinterpret_cast<const float4*>(&xs[rg * 8 + r][kq * 4]);
        acc[r] = fmaf(xv.x, w0, acc[r]);
        acc[r] = fmaf(xv.y, w1, acc[r]);
        acc[r] = fmaf(xv.z, w2, acc[r]);
        acc[r] = fmaf(xv.w, w3, acc[r]);
      }
    }
    __syncthreads();
  }
  float* out = hp + (size_t)blockIdx.y * N_NODES * HID;
#pragma unroll
  for (int r = 0; r < 8; ++r) {
    int row = row0 + rg * 8 + r;
    if (row < N_NODES) out[(size_t)row * HID + col] = acc[r];
  }
}

// ------- GEMM 2: h = relu(hp0+hp1+b_in); xl = h@W_l + b_l ; xr = h@W_r + b_r -------
__global__ __launch_bounds__(256) void k_gemm_lr(const float* __restrict__ hp,
    const float* __restrict__ bin,
    const float* __restrict__ Wl, const float* __restrict__ bl,
    const float* __restrict__ Wr, const float* __restrict__ br,
    float* __restrict__ xl, float* __restrict__ xr) {
  const int col  = threadIdx.x & 127;
  const int rg   = threadIdx.x >> 7;       // 0..1 (4 rows each)
  const int row0 = blockIdx.x * 8;
  __shared__ float hs[8][128];
  const float* hp0 = hp;
  const float* hp1 = hp + (size_t)N_NODES * HID;
#pragma unroll
  for (int t = 0; t < 4; ++t) {
    int idx = threadIdx.x + t * 256;
    int r = idx >> 7, c = idx & 127;
    size_t g = (size_t)(row0 + r) * HID + c;
    hs[r][c] = fmaxf(hp0[g] + hp1[g] + bin[c], 0.f);
  }
  __syncthreads();
  float accl[4] = {0.f,0.f,0.f,0.f};
  float accr[4] = {0.f,0.f,0.f,0.f};
#pragma unroll 4
  for (int kq = 0; kq < 32; ++kq) {
    float wl0 = Wl[(kq*4+0)*HID + col], wr0 = Wr[(kq*4+0)*HID + col];
    float wl1 = Wl[(kq*4+1)*HID + col], wr1 = Wr[(kq*4+1)*HID + col];
    float wl2 = Wl[(kq*4+2)*HID + col], wr2 = Wr[(kq*4+2)*HID + col];
    float wl3 = Wl[(kq*4+3)*HID + col], wr3 = Wr[(kq*4+3)*HID + col];
#pragma unroll
    for (int r = 0; r < 4; ++r) {
      const float4 xv = *reinterpret_cast<const float4*>(&hs[rg*4 + r][kq*4]);
      accl[r] = fmaf(xv.x, wl0, accl[r]); accr[r] = fmaf(xv.x, wr0, accr[r]);
      accl[r] = fmaf(xv.y, wl1, accl[r]); accr[r] = fmaf(xv.y, wr1, accr[r]);
      accl[r] = fmaf(xv.z, wl2, accl[r]); accr[r] = fmaf(xv.z, wr2, accr[r]);
      accl[r] = fmaf(xv.w, wl3, accl[r]); accr[r] = fmaf(xv.w, wr3, accr[r]);
    }
  }
  const float biasl = bl[col], biasr = br[col];
#pragma unroll
  for (int r = 0; r < 4; ++r) {
    int row = row0 + rg * 4 + r;
    xl[(size_t)row * HID + col] = accl[r] + biasl;
    xr[(size_t)row * HID + col] = accr[r] + biasr;
  }
}

// ---------------- CSR build: hist -> scan -> fill ----------------
__global__ __launch_bounds__(256) void k_hist(const int* __restrict__ ei, int E, int ET,
                                              unsigned* __restrict__ deg) {
  int e = blockIdx.x * blockDim.x + threadIdx.x;
  if (e >= ET) return;
  const int dst = (e < E) ? ei[E + e] : (e - E);
  atomicAdd(&deg[dst], 1u);
}

__global__ __launch_bounds__(256) void k_scan(const unsigned* __restrict__ deg,
    unsigned* __restrict__ off, unsigned* __restrict__ cursor) {
  __shared__ unsigned part[256];
  const int t = threadIdx.x;
  unsigned s = 0;
#pragma unroll
  for (int i = 0; i < 20; ++i) { int d = t * 20 + i; if (d < N_NODES) s += deg[d]; }
  part[t] = s;
  __syncthreads();
  for (int st = 1; st < 256; st <<= 1) {
    unsigned val = (t >= st) ? part[t - st] : 0u;
    __syncthreads();
    part[t] += val;
    __syncthreads();
  }
  unsigned run = (t == 0) ? 0u : part[t - 1];
  for (int i = 0; i < 20; ++i) {
    int d = t * 20 + i;
    if (d < N_NODES) { off[d] = run; cursor[d] = run; run += deg[d]; }
  }
}

__global__ __launch_bounds__(256) void k_fill(const int* __restrict__ ei, int E, int ET,
    unsigned* __restrict__ cursor, unsigned* __restrict__ csr) {
  int e = blockIdx.x * blockDim.x + threadIdx.x;
  if (e >= ET) return;
  const int src = (e < E) ? ei[e]     : (e - E);
  const int dst = (e < E) ? ei[E + e] : (e - E);
  unsigned pos = atomicAdd(&cursor[dst], 1u);
  csr[pos] = (unsigned)src;
}

// -------- per-dst single-pass online-softmax aggregation: v = leaky(GATv2 out) --------
__global__ __launch_bounds__(64) void k_agg(const float* __restrict__ xl,
    const float* __restrict__ xr, const float* __restrict__ att,
    const float* __restrict__ gb, const unsigned* __restrict__ off,
    const unsigned* __restrict__ deg, const unsigned* __restrict__ csr,
    float* __restrict__ v) {
  const int dst  = blockIdx.x;
  const int lane = threadIdx.x;                 // cols 2*lane, 2*lane+1
  const unsigned o  = off[dst];
  const unsigned dg = deg[dst];
  const float2 xr2 = *reinterpret_cast<const float2*>(&xr[(size_t)dst * HID + lane * 2]);
  const float2 at2 = *reinterpret_cast<const float2*>(&att[lane * 2]);
  float m = -INFINITY, s = 0.f;
  float2 acc = make_float2(0.f, 0.f);
  for (unsigned t = 0; t < dg; ++t) {
    const unsigned src = csr[o + t];
    const float2 xl2 = *reinterpret_cast<const float2*>(&xl[(size_t)src * HID + lane * 2]);
    float sa = leaky(xl2.x + xr2.x) * at2.x + leaky(xl2.y + xr2.y) * at2.y;
#pragma unroll
    for (int st = 1; st < 64; st <<= 1) sa += __shfl_xor(sa, st);
    if (sa > m) {            // wave-uniform branch (sa identical on all lanes)
      const float sc = __expf(m - sa);     // first iter: exp(-inf)=0
      s = s * sc + 1.f;
      acc.x = acc.x * sc + xl2.x;
      acc.y = acc.y * sc + xl2.y;
      m = sa;
    } else {
      const float ex = __expf(sa - m);
      s += ex;
      acc.x = fmaf(ex, xl2.x, acc.x);
      acc.y = fmaf(ex, xl2.y, acc.y);
    }
  }
  const float inv = 1.f / s;
  const float2 gb2 = *reinterpret_cast<const float2*>(&gb[lane * 2]);
  float2 r;
  r.x = leaky(fmaf(acc.x, inv, gb2.x));
  r.y = leaky(fmaf(acc.y, inv, gb2.y));
  *reinterpret_cast<float2*>(&v[(size_t)dst * HID + lane * 2]) = r;
}

// ---- out128[j] = sum_i v[i]*W1[i*128+j] : 328 MB stream, slab per block ----
__global__ __launch_bounds__(256) void k_matvec(const float* __restrict__ v,
    const float* __restrict__ W1, float* __restrict__ out128) {
  const int c  = threadIdx.x & 31;   // col quad
  const int rr = threadIdx.x >> 5;   // 0..7
  const int base = blockIdx.x * 320; // 2000 blocks * 320 rows = 640000
  __shared__ float vs[320];
  if (threadIdx.x < 256) vs[threadIdx.x] = v[base + threadIdx.x];
  if (threadIdx.x < 64)  vs[256 + threadIdx.x] = v[base + 256 + threadIdx.x];
  __syncthreads();
  float4 acc = make_float4(0.f, 0.f, 0.f, 0.f);
#pragma unroll 8
  for (int it = 0; it < 40; ++it) {
    const int r = it * 8 + rr;
    const float4 w = *reinterpret_cast<const float4*>(&W1[(size_t)(base + r) * HID + c * 4]);
    const float vv = vs[r];
    acc.x = fmaf(vv, w.x, acc.x);
    acc.y = fmaf(vv, w.y, acc.y);
    acc.z = fmaf(vv, w.z, acc.z);
    acc.w = fmaf(vv, w.w, acc.w);
  }
  __shared__ float part[8][128];
  *reinterpret_cast<float4*>(&part[rr][c * 4]) = acc;
  __syncthreads();
  if (rr == 0) {
    float4 sum = make_float4(0.f, 0.f, 0.f, 0.f);
#pragma unroll
    for (int g = 0; g < 8; ++g) {
      const float4 p = *reinterpret_cast<const float4*>(&part[g][c * 4]);
      sum.x += p.x; sum.y += p.y; sum.z += p.z; sum.w += p.w;
    }
    atomicAdd(&out128[c * 4 + 0], sum.x);
    atomicAdd(&out128[c * 4 + 1], sum.y);
    atomicAdd(&out128[c * 4 + 2], sum.z);
    atomicAdd(&out128[c * 4 + 3], sum.w);
  }
}

// y = relu(out128 + b1); out = y @ W2 + b2
__global__ void k_final(const float* __restrict__ out128, const float* __restrict__ b1,
                        const float* __restrict__ W2, const float* __restrict__ b2,
                        float* __restrict__ out) {
  __shared__ float red[128];
  const int j = threadIdx.x;
  const float y = fmaxf(out128[j] + b1[j], 0.f);
  red[j] = y * W2[j];
  __syncthreads();
  if (j == 0) {
    float t = 0.f;
    for (int k = 0; k < 128; ++k) t += red[k];
    out[0] = t + b2[0];
  }
}

extern "C" void kernel_launch(void* const* d_in, const int* in_sizes, int n_in,
                              void* d_out, int out_size, void* d_ws, size_t ws_size,
                              hipStream_t stream) {
  const float* x    = (const float*)d_in[0];
  const int*   ei   = (const int*)  d_in[1];
  const float* W_in = (const float*)d_in[2];
  const float* b_in = (const float*)d_in[3];
  const float* W_l  = (const float*)d_in[4];
  const float* b_l  = (const float*)d_in[5];
  const float* W_r  = (const float*)d_in[6];
  const float* b_r  = (const float*)d_in[7];
  const float* att  = (const float*)d_in[8];
  const float* gb   = (const float*)d_in[9];
  const float* W1   = (const float*)d_in[10];
  const float* b1   = (const float*)d_in[11];
  const float* W2   = (const float*)d_in[12];
  const float* b2   = (const float*)d_in[13];
  float* out = (float*)d_out;

  const int E  = in_sizes[1] / 2;
  const int ET = E + N_NODES;

  float* ws = (float*)d_ws;
  float*    hp     = ws;                         // 2 * 640000 (split-K partials)
  float*    xl     = ws + 1280000;               // 640000
  float*    xr     = ws + 1920000;               // 640000
  float*    v      = ws + 2560000;               // 640000
  unsigned* deg    = (unsigned*)(ws + 3200000);  // 5000
  unsigned* off    = deg + N_NODES;              // 5000
  unsigned* cursor = off + N_NODES;              // 5000
  unsigned* csr    = cursor + N_NODES;           // ET
  float*    out128 = (float*)(csr + ET);         // 128

  hipMemsetAsync(deg,    0, (size_t)N_NODES * sizeof(unsigned), stream);
  hipMemsetAsync(out128, 0, (size_t)HID * sizeof(float), stream);

  k_gemm_in <<<dim3((N_NODES + 15) / 16, 2), 256, 0, stream>>>(x, W_in, hp);
  k_gemm_lr <<<N_NODES / 8, 256, 0, stream>>>(hp, b_in, W_l, b_l, W_r, b_r, xl, xr);
  k_hist    <<<(ET + 255) / 256, 256, 0, stream>>>(ei, E, ET, deg);
  k_scan    <<<1, 256, 0, stream>>>(deg, off, cursor);
  k_fill    <<<(ET + 255) / 256, 256, 0, stream>>>(ei, E, ET, cursor, csr);
  k_agg     <<<N_NODES, 64, 0, stream>>>(xl, xr, att, gb, off, deg, csr, v);
  k_matvec  <<<2000, 256, 0, stream>>>(v, W1, out128);
  k_final   <<<1, 128, 0, stream>>>(out128, b1, W2, b2, out);
}